// Round 7
// baseline (1557.041 us; speedup 1.0000x reference)
//
#include <hip/hip_runtime.h>
#include <stdint.h>

typedef unsigned long long u64;

static constexpr int CIN  = 256;
static constexpr int HWD  = 56;
static constexpr int NPIX = HWD * HWD;   // 3136
static constexpr int NB   = 128;
static constexpr int NO   = 128;

// ---------------------------------------------------------------------------
// Pack weights: bit = 1 iff w < 0. Layout wb[(o*9 + t)*4 + cw], t = dh*3+dw.
// Also alpha[o] = mean |w[o,:,:,:]| over 2304 elements.
// grid = 128 blocks (one per o), block = 256 (4 waves; wave cw handles
// channels cw*64 .. cw*64+63, lane = channel within group).
// ---------------------------------------------------------------------------
__global__ __launch_bounds__(256) void pack_w_kernel(
    const float* __restrict__ w, u64* __restrict__ wb,
    float* __restrict__ alpha) {
  const int o    = blockIdx.x;
  const int tid  = threadIdx.x;
  const int cw   = tid >> 6;
  const int lane = tid & 63;
  const int c    = cw * 64 + lane;
  const float* wp = w + (size_t)(o * CIN + c) * 9;
  float s = 0.f;
#pragma unroll
  for (int t = 0; t < 9; ++t) {
    float v = wp[t];
    s += fabsf(v);
    u64 m = __ballot(v < 0.f);
    if (lane == 0) wb[(o * 9 + t) * 4 + cw] = m;
  }
#pragma unroll
  for (int off = 32; off; off >>= 1) s += __shfl_down(s, off);
  __shared__ float red[4];
  if (lane == 0) red[cw] = s;
  __syncthreads();
  if (tid == 0) alpha[o] = (red[0] + red[1] + red[2] + red[3]) * (1.f / 2304.f);
}

// ---------------------------------------------------------------------------
// Pack activations: bit = 1 iff x < 0. Layout xb[((b*56+h)*56+w)*4 + cw].
// Also accumulate beta_sum[b] = sum |x[b,:,:,:]| (atomicAdd of block partials).
// grid = (128, 56) -> (b, h). block = 256: wave cw, lane = channel.
// Each lane streams 56 contiguous floats (its channel's row h).
// ---------------------------------------------------------------------------
__global__ __launch_bounds__(256) void pack_x_kernel(
    const float* __restrict__ x, u64* __restrict__ xb,
    float* __restrict__ beta_sum) {
  const int b    = blockIdx.x;
  const int h    = blockIdx.y;
  const int tid  = threadIdx.x;
  const int cw   = tid >> 6;
  const int lane = tid & 63;
  const int c    = cw * 64 + lane;
  const float* xp = x + (size_t)(b * CIN + c) * NPIX + h * HWD;
  u64* xbp = xb + ((size_t)(b * HWD + h) * HWD) * 4 + cw;
  float s = 0.f;
  for (int w = 0; w < HWD; ++w) {
    float v = xp[w];
    s += fabsf(v);
    u64 m = __ballot(v < 0.f);
    if (lane == 0) xbp[(size_t)w * 4] = m;
  }
#pragma unroll
  for (int off = 32; off; off >>= 1) s += __shfl_down(s, off);
  __shared__ float red[4];
  if (lane == 0) red[cw] = s;
  __syncthreads();
  if (tid == 0) atomicAdd(&beta_sum[b], red[0] + red[1] + red[2] + red[3]);
}

// ---------------------------------------------------------------------------
// Binary conv via XOR+popcount.
// Each thread: one (b, h, w) pixel. Loads 9 taps x 4 u64 of x-bits into
// registers, loops all 128 output channels. Per valid tap the +/-1 dot over
// 256 channels is 256 - 2*popc(x^w); padding taps contribute exactly 0
// (handled by the validity select + nvalid*256 base).
// Weight reads are wave-uniform -> scalar loads through K$.
// out[b,o,h,w] = int_dot * alpha[b] * beta[b]   (batch-indexed alpha!)
// ---------------------------------------------------------------------------
__global__ __launch_bounds__(256) void conv_kernel(
    const u64* __restrict__ xb, const u64* __restrict__ wb,
    const float* __restrict__ alpha, const float* __restrict__ beta_sum,
    float* __restrict__ out) {
  const int gid = blockIdx.x * 256 + threadIdx.x;   // [0, NB*NPIX)
  const int b  = gid / NPIX;
  const int hw = gid - b * NPIX;
  const int h  = hw / HWD;
  const int w  = hw - h * HWD;

  const float scale =
      alpha[b] * beta_sum[b] * (1.f / ((float)CIN * (float)NPIX));

  u64  xv[9][4];
  bool valid[9];
  int  nvalid = 0;
#pragma unroll
  for (int dh = 0; dh < 3; ++dh) {
#pragma unroll
    for (int dw = 0; dw < 3; ++dw) {
      const int t  = dh * 3 + dw;
      const int hh = h + dh - 1;
      const int ww = w + dw - 1;
      const bool v = ((unsigned)hh < (unsigned)HWD) &&
                     ((unsigned)ww < (unsigned)HWD);
      valid[t] = v;
      nvalid += v ? 1 : 0;
      if (v) {
        const u64* p = xb + ((size_t)((b * HWD + hh) * HWD + ww)) * 4;
#pragma unroll
        for (int k = 0; k < 4; ++k) xv[t][k] = p[k];
      } else {
#pragma unroll
        for (int k = 0; k < 4; ++k) xv[t][k] = 0ull;
      }
    }
  }

  const int cbase = nvalid * CIN;
  float* op = out + (size_t)b * NO * NPIX + hw;

  for (int o = 0; o < NO; ++o) {
    const u64* wp = wb + o * 36;   // uniform address -> s_load
    int mism = 0;
#pragma unroll
    for (int t = 0; t < 9; ++t) {
      int pc = 0;
#pragma unroll
      for (int k = 0; k < 4; ++k) pc += __popcll(xv[t][k] ^ wp[t * 4 + k]);
      mism += valid[t] ? pc : 0;
    }
    op[(size_t)o * NPIX] = (float)(cbase - 2 * mism) * scale;
  }
}

// ---------------------------------------------------------------------------
// Workspace layout:
//   [0,    512) : beta_sum  (128 f32, atomically accumulated -> must zero)
//   [512, 1024) : alpha     (128 f32)
//   [1024, 1024+36864) : wb (128*9*4 u64 = 36 KB)
//   [40960, 40960+12845056) : xb (128*56*56*4 u64 = 12.85 MB)
// Total ~12.3 MiB.
// ---------------------------------------------------------------------------
extern "C" void kernel_launch(void* const* d_in, const int* in_sizes, int n_in,
                              void* d_out, int out_size, void* d_ws,
                              size_t ws_size, hipStream_t stream) {
  const float* x  = (const float*)d_in[0];
  const float* wt = (const float*)d_in[1];
  // d_in[2] = stride(1), d_in[3] = padding(1): fixed by setup_inputs.

  char* ws = (char*)d_ws;
  float* beta_sum = (float*)ws;
  float* alpha    = (float*)(ws + 512);
  u64*   wb       = (u64*)(ws + 1024);
  u64*   xb       = (u64*)(ws + 40960);
  float* out      = (float*)d_out;

  hipMemsetAsync(beta_sum, 0, NB * sizeof(float), stream);
  pack_w_kernel<<<NO, 256, 0, stream>>>(wt, wb, alpha);
  pack_x_kernel<<<dim3(NB, HWD), 256, 0, stream>>>(x, xb, beta_sum);
  conv_kernel<<<(NB * NPIX) / 256, 256, 0, stream>>>(xb, wb, alpha, beta_sum,
                                                     out);
}

// Round 9
// 932.645 us; speedup vs baseline: 1.6695x; 1.6695x over previous
//
#include <hip/hip_runtime.h>
#include <stdint.h>

typedef unsigned long long u64;

static constexpr int CIN  = 256;
static constexpr int HWD  = 56;
static constexpr int NPIX = HWD * HWD;   // 3136
static constexpr int NB   = 128;
static constexpr int NO   = 128;

// Interior geometry: h,w in [1,54]; pairs along w.
static constexpr int IH     = 54;
static constexpr int IPAIRS = 27;            // (1,2),(3,4)..(53,54)
static constexpr int IPERB  = IH * IPAIRS;   // 1458
static constexpr int NEDGE  = 220;           // 4*56-4 boundary pixels

// ---------------------------------------------------------------------------
// Pack weights: bit = 1 iff w < 0. Layout wb[(o*9 + t)*4 + cw], t = dh*3+dw.
// alpha[o] = mean |w| over 2304. grid=128 (o), block=256 (wave cw = chan grp).
// ---------------------------------------------------------------------------
__global__ __launch_bounds__(256) void pack_w_kernel(
    const float* __restrict__ w, u64* __restrict__ wb,
    float* __restrict__ alpha) {
  const int o    = blockIdx.x;
  const int tid  = threadIdx.x;
  const int cw   = tid >> 6;
  const int lane = tid & 63;
  const int c    = cw * 64 + lane;
  const float* wp = w + (size_t)(o * CIN + c) * 9;
  float s = 0.f;
#pragma unroll
  for (int t = 0; t < 9; ++t) {
    float v = wp[t];
    s += fabsf(v);
    u64 m = __ballot(v < 0.f);
    if (lane == 0) wb[(o * 9 + t) * 4 + cw] = m;
  }
#pragma unroll
  for (int off = 32; off; off >>= 1) s += __shfl_down(s, off);
  __shared__ float red[4];
  if (lane == 0) red[cw] = s;
  __syncthreads();
  if (tid == 0) alpha[o] = (red[0] + red[1] + red[2] + red[3]) * (1.f / 2304.f);
}

// ---------------------------------------------------------------------------
// Pack activations, COALESCED: lane = pixel, loop channels.
// Wave reads 64 consecutive pixels (256 B aligned contiguous) per channel.
// Lane builds its 4 sign-words: bit (c&63) of word (c>>6) = signbit(x).
// xb layout unchanged: xb[(b*NPIX + pix)*4 + cw].
// grid = (49, 128) -> (pixel tile, b), block = 64 (1 wave).
// Fetch: exactly one pass over x = 411 MB (was 2.9 GB).
// ---------------------------------------------------------------------------
__global__ __launch_bounds__(64) void pack_x_kernel(
    const float* __restrict__ x, u64* __restrict__ xb,
    float* __restrict__ beta_sum) {
  const int lane = threadIdx.x;
  const int pix  = blockIdx.x * 64 + lane;
  const int b    = blockIdx.y;
  const float* xp = x + (size_t)b * CIN * NPIX + pix;
  float s = 0.f;
  u64 bits[4];
#pragma unroll
  for (int cw = 0; cw < 4; ++cw) {
    u64 acc = 0;
#pragma unroll
    for (int k = 0; k < 64; ++k) {
      const int c = cw * 64 + k;
      const uint32_t u = __float_as_uint(xp[(size_t)c * NPIX]);
      s += __uint_as_float(u & 0x7fffffffu);            // |x|
      acc |= (u64)(u >> 31) << k;                       // sign bit
    }
    bits[cw] = acc;
  }
  u64* xbp = xb + ((size_t)b * NPIX + pix) * 4;         // 32 B/lane contiguous
  xbp[0] = bits[0]; xbp[1] = bits[1]; xbp[2] = bits[2]; xbp[3] = bits[3];
#pragma unroll
  for (int off = 32; off; off >>= 1) s += __shfl_down(s, off);
  if (lane == 0) atomicAdd(&beta_sum[b], s);
}

// ---------------------------------------------------------------------------
// Interior conv (h,w in [1,54]): branch-free, all 9 taps valid.
// Weights staged once per block into LDS (36 KB); inner reads are
// same-address across the wave -> bank-conflict-free broadcast.
// Each thread computes TWO w-adjacent outputs (w0 odd, w0+1): the 3x4
// x-word neighborhood (48 u64) serves both, halving LDS reads per output.
// dot = 2304 - 2*mism (exact); out = dot * alpha[b]*beta[b].
// grid = 729 blocks x 256 = 128 b * 1458 pairs, exact.
// ---------------------------------------------------------------------------
__global__ __launch_bounds__(256) void conv_int_kernel(
    const u64* __restrict__ xb, const u64* __restrict__ wb,
    const float* __restrict__ alpha, const float* __restrict__ beta_sum,
    float* __restrict__ out) {
  __shared__ __align__(16) u64 wlds[NO * 36];           // 36864 B
  {
    const float4* src = (const float4*)wb;
    float4* dst = (float4*)wlds;
#pragma unroll
    for (int i = 0; i < 9; ++i)
      dst[threadIdx.x + i * 256] = src[threadIdx.x + i * 256];
  }
  __syncthreads();

  const int idx = blockIdx.x * 256 + threadIdx.x;       // [0, 186624)
  const int b   = idx / IPERB;
  const int r   = idx - b * IPERB;
  const int hr  = r / IPAIRS;
  const int h   = 1 + hr;
  const int w0  = 1 + 2 * (r - hr * IPAIRS);            // odd, in [1,53]

  const float scale =
      alpha[b] * beta_sum[b] * (1.f / ((float)CIN * (float)NPIX));

  // xv[dh][c][k]: x-words at (h-1+dh, w0-1+c)
  u64 xv[3][4][4];
#pragma unroll
  for (int dh = 0; dh < 3; ++dh) {
#pragma unroll
    for (int c = 0; c < 4; ++c) {
      const u64* p =
          xb + ((size_t)((b * HWD + (h - 1 + dh)) * HWD + (w0 - 1 + c))) * 4;
#pragma unroll
      for (int k = 0; k < 4; ++k) xv[dh][c][k] = p[k];
    }
  }

  float* op = out + (size_t)b * NO * NPIX + h * HWD + w0;
  for (int o = 0; o < NO; ++o) {
    const u64* wp = &wlds[o * 36];
    int m0 = 0, m1 = 0;
#pragma unroll
    for (int t = 0; t < 9; ++t) {
      const int dh = t / 3, dw = t % 3;
#pragma unroll
      for (int k = 0; k < 4; ++k) {
        const u64 wv = wp[t * 4 + k];
        m0 += __popcll(xv[dh][dw][k] ^ wv);
        m1 += __popcll(xv[dh][dw + 1][k] ^ wv);
      }
    }
    op[(size_t)o * NPIX]     = (float)(2304 - 2 * m0) * scale;
    op[(size_t)o * NPIX + 1] = (float)(2304 - 2 * m1) * scale;
  }
}

// ---------------------------------------------------------------------------
// Edge conv: the 220 boundary pixels per image (7% of work), masked-tap
// logic identical to the round-0 proven kernel. grid = 110 x 256 exact.
// ---------------------------------------------------------------------------
__global__ __launch_bounds__(256) void conv_edge_kernel(
    const u64* __restrict__ xb, const u64* __restrict__ wb,
    const float* __restrict__ alpha, const float* __restrict__ beta_sum,
    float* __restrict__ out) {
  const int idx = blockIdx.x * 256 + threadIdx.x;       // [0, 28160)
  const int b   = idx / NEDGE;
  const int e   = idx - b * NEDGE;
  int h, w;
  if (e < 56)       { h = 0;        w = e; }
  else if (e < 112) { h = 55;       w = e - 56; }
  else if (e < 166) { h = e - 111;  w = 0; }            // h in [1,54]
  else              { h = e - 165;  w = 55; }           // h in [1,54]

  const float scale =
      alpha[b] * beta_sum[b] * (1.f / ((float)CIN * (float)NPIX));

  u64  xv[9][4];
  bool valid[9];
  int  nvalid = 0;
#pragma unroll
  for (int dh = 0; dh < 3; ++dh) {
#pragma unroll
    for (int dw = 0; dw < 3; ++dw) {
      const int t  = dh * 3 + dw;
      const int hh = h + dh - 1;
      const int ww = w + dw - 1;
      const bool v = ((unsigned)hh < (unsigned)HWD) &&
                     ((unsigned)ww < (unsigned)HWD);
      valid[t] = v;
      nvalid += v ? 1 : 0;
      if (v) {
        const u64* p = xb + ((size_t)((b * HWD + hh) * HWD + ww)) * 4;
#pragma unroll
        for (int k = 0; k < 4; ++k) xv[t][k] = p[k];
      } else {
#pragma unroll
        for (int k = 0; k < 4; ++k) xv[t][k] = 0ull;
      }
    }
  }

  const int cbase = nvalid * CIN;
  float* op = out + (size_t)b * NO * NPIX + h * HWD + w;
  for (int o = 0; o < NO; ++o) {
    const u64* wp = wb + o * 36;
    int mism = 0;
#pragma unroll
    for (int t = 0; t < 9; ++t) {
      int pc = 0;
#pragma unroll
      for (int k = 0; k < 4; ++k) pc += __popcll(xv[t][k] ^ wp[t * 4 + k]);
      mism += valid[t] ? pc : 0;
    }
    op[(size_t)o * NPIX] = (float)(cbase - 2 * mism) * scale;
  }
}

// ---------------------------------------------------------------------------
// Workspace: [0,512) beta_sum | [512,1024) alpha | [1024,+36 KB) wb |
//            [40960,+12.85 MB) xb
// ---------------------------------------------------------------------------
extern "C" void kernel_launch(void* const* d_in, const int* in_sizes, int n_in,
                              void* d_out, int out_size, void* d_ws,
                              size_t ws_size, hipStream_t stream) {
  const float* x  = (const float*)d_in[0];
  const float* wt = (const float*)d_in[1];

  char* ws = (char*)d_ws;
  float* beta_sum = (float*)ws;
  float* alpha    = (float*)(ws + 512);
  u64*   wb       = (u64*)(ws + 1024);
  u64*   xb       = (u64*)(ws + 40960);
  float* out      = (float*)d_out;

  hipMemsetAsync(beta_sum, 0, NB * sizeof(float), stream);
  pack_w_kernel<<<NO, 256, 0, stream>>>(wt, wb, alpha);
  pack_x_kernel<<<dim3(49, NB), 64, 0, stream>>>(x, xb, beta_sum);
  conv_int_kernel<<<(NB * IPERB) / 256, 256, 0, stream>>>(xb, wb, alpha,
                                                          beta_sum, out);
  conv_edge_kernel<<<(NB * NEDGE) / 256, 256, 0, stream>>>(xb, wb, alpha,
                                                           beta_sum, out);
}